// Round 1
// baseline (111.022 us; speedup 1.0000x reference)
//
#include <hip/hip_runtime.h>

// Problem constants (from setup_inputs): B=2, L=32, C=8, H=W=64
#define BB 2
#define LL 32
#define CC 8
#define HH 64
#define WW 64
#define HWL (HH * WW)

// Kernel 1: sequential cumsum of flows along L (axis 1).
// flows layout: (B, L, 2, H, W). One thread per (b, comp, y, x).
__global__ __launch_bounds__(256) void cumsum_flows_kernel(
    const float* __restrict__ flows, float* __restrict__ cum) {
    int idx = blockIdx.x * blockDim.x + threadIdx.x;  // over B*2*H*W = 32768
    if (idx >= BB * 2 * HWL) return;
    int pix  = idx & (HWL - 1);
    int rest = idx >> 12;          // b*2 + comp
    int comp = rest & 1;
    int b    = rest >> 1;
    size_t base = ((size_t)(b * LL) * 2 + comp) * HWL + pix;
    float acc = 0.0f;
    for (int l = 0; l < LL; ++l) {
        acc += flows[base + (size_t)l * 2 * HWL];
        cum[base + (size_t)l * 2 * HWL] = acc;
    }
}

// Kernel 2: one thread per (b, t, y, x). Loops k = 0..t, accumulating the
// bilinear warp of image (b,k) at displacement cum[b,t]-cum[b,k] into C=8
// register accumulators.
__global__ __launch_bounds__(256) void warp_pscan_kernel(
    const float* __restrict__ cum, const float* __restrict__ images,
    float* __restrict__ out) {
    int idx = blockIdx.x * blockDim.x + threadIdx.x;  // over B*L*H*W = 262144
    if (idx >= BB * LL * HWL) return;
    int x  = idx & (WW - 1);
    int y  = (idx >> 6) & (HH - 1);
    int tl = (idx >> 12) & (LL - 1);
    int b  = idx >> 17;
    // Load-balance remap: groups g and g+16 pair to t and 31-t so any
    // contiguous window of block-groups has ~uniform total work.
    int t = (tl < 16) ? tl : (47 - tl);

    // Base grid: exact multiples of 1/64, matches jnp.linspace bitwise.
    float gx = -1.0f + (float)(2 * x + 1) * (1.0f / WW);
    float gy = -1.0f + (float)(2 * y + 1) * (1.0f / HH);

    int pix = y * WW + x;
    const float* cumb = cum + (size_t)b * LL * 2 * HWL + pix;
    float ctx = cumb[(size_t)t * 2 * HWL];
    float cty = cumb[(size_t)t * 2 * HWL + HWL];

    float acc[CC];
#pragma unroll
    for (int c = 0; c < CC; ++c) acc[c] = 0.0f;

    const float* imgb = images + (size_t)b * LL * CC * HWL;

    for (int k = 0; k <= t; ++k) {
        float dx = ctx - cumb[(size_t)k * 2 * HWL];
        float dy = cty - cumb[(size_t)k * 2 * HWL + HWL];
        float g0 = gx + dx;
        float g1 = gy + dy;
        // x wrap: jnp.remainder(g0 + 1, 2) - 1  (fmod + adjust, bit-exact)
        float m = fmodf(g0 + 1.0f, 2.0f);
        if (m < 0.0f) m += 2.0f;
        float gxw = m - 1.0f;
        // Same op order as reference:
        float ix = ((gxw + 1.0f) * (float)WW - 1.0f) * 0.5f;
        float iy = ((g1 + 1.0f) * (float)HH - 1.0f) * 0.5f;
        float x0f = floorf(ix), y0f = floorf(iy);
        float wx1 = ix - x0f, wy1 = iy - y0f;
        float wx0 = 1.0f - wx1, wy0 = 1.0f - wy1;
        int x0 = (int)x0f, y0 = (int)y0f;
        int x1 = x0 + 1, y1 = y0 + 1;
        bool vx0 = (x0 >= 0) & (x0 < WW);
        bool vx1 = (x1 >= 0) & (x1 < WW);
        bool vy0 = (y0 >= 0) & (y0 < HH);
        bool vy1 = (y1 >= 0) & (y1 < HH);
        int x0c = min(max(x0, 0), WW - 1), x1c = min(max(x1, 0), WW - 1);
        int y0c = min(max(y0, 0), HH - 1), y1c = min(max(y1, 0), HH - 1);
        float w00 = (vx0 && vy0) ? wx0 * wy0 : 0.0f;
        float w10 = (vx1 && vy0) ? wx1 * wy0 : 0.0f;
        float w01 = (vx0 && vy1) ? wx0 * wy1 : 0.0f;
        float w11 = (vx1 && vy1) ? wx1 * wy1 : 0.0f;
        int o00 = y0c * WW + x0c, o10 = y0c * WW + x1c;
        int o01 = y1c * WW + x0c, o11 = y1c * WW + x1c;
        const float* img = imgb + (size_t)k * CC * HWL;
#pragma unroll
        for (int c = 0; c < CC; ++c) {
            const float* ic = img + (size_t)c * HWL;
            acc[c] += w00 * ic[o00] + w10 * ic[o10] + w01 * ic[o01] +
                      w11 * ic[o11];
        }
    }

    float* op = out + ((size_t)(b * LL + t) * CC) * HWL + pix;
#pragma unroll
    for (int c = 0; c < CC; ++c) op[(size_t)c * HWL] = acc[c];
}

extern "C" void kernel_launch(void* const* d_in, const int* in_sizes, int n_in,
                              void* d_out, int out_size, void* d_ws,
                              size_t ws_size, hipStream_t stream) {
    const float* flows  = (const float*)d_in[0];
    const float* images = (const float*)d_in[1];
    float* out = (float*)d_out;
    float* cum = (float*)d_ws;  // B*L*2*H*W floats = 2 MiB

    int n1 = BB * 2 * HWL;
    cumsum_flows_kernel<<<(n1 + 255) / 256, 256, 0, stream>>>(flows, cum);

    int n2 = BB * LL * HWL;
    warp_pscan_kernel<<<(n2 + 255) / 256, 256, 0, stream>>>(cum, images, out);
}

// Round 2
// 100.642 us; speedup vs baseline: 1.1031x; 1.1031x over previous
//
#include <hip/hip_runtime.h>

// Problem constants: B=2, L=32, C=8, H=W=64
#define BB 2
#define LL 32
#define CC 8
#define HH 64
#define WW 64
#define HWL (HH * WW)

// Kernel 1: cumsum of flows along L, stored TRANSPOSED as (b, pix, l, {x,y})
// so a thread's per-k cum values are contiguous (float4 = 2 k-steps).
__global__ __launch_bounds__(256) void cumsum_T_kernel(
    const float* __restrict__ flows, float* __restrict__ cumT) {
    int idx = blockIdx.x * blockDim.x + threadIdx.x;  // over B*H*W = 8192
    if (idx >= BB * HWL) return;
    int pix = idx & (HWL - 1);
    int b   = idx >> 12;
    const float* f = flows + (size_t)b * LL * 2 * HWL + pix;
    float* o = cumT + ((size_t)b * HWL + pix) * LL * 2;
    float ax = 0.0f, ay = 0.0f;
    for (int l = 0; l < LL; ++l) {
        ax += f[(size_t)l * 2 * HWL];
        ay += f[(size_t)l * 2 * HWL + HWL];
        o[2 * l]     = ax;
        o[2 * l + 1] = ay;
    }
}

// Kernel 2: repack images (b,l,c,y,x) -> channel-last (b,l,y,x,c).
// Reads coalesced per channel; writes 32B/lane coalesced.
__global__ __launch_bounds__(256) void repack_cl_kernel(
    const float* __restrict__ img, float* __restrict__ imgcl) {
    int idx = blockIdx.x * blockDim.x + threadIdx.x;  // over B*L*H*W = 262144
    if (idx >= BB * LL * HWL) return;
    int pix = idx & (HWL - 1);
    int bl  = idx >> 12;
    const float* ip = img + (size_t)bl * CC * HWL + pix;
    float4 lo, hi;
    lo.x = ip[0];
    lo.y = ip[(size_t)1 * HWL];
    lo.z = ip[(size_t)2 * HWL];
    lo.w = ip[(size_t)3 * HWL];
    hi.x = ip[(size_t)4 * HWL];
    hi.y = ip[(size_t)5 * HWL];
    hi.z = ip[(size_t)6 * HWL];
    hi.w = ip[(size_t)7 * HWL];
    float4* op = reinterpret_cast<float4*>(imgcl + (size_t)idx * CC);
    op[0] = lo;
    op[1] = hi;
}

// Kernel 3: one thread per (cg, b, t, y, x); cg in {0,1} selects channels
// 0-3 / 4-7 (doubles wave count for latency hiding). Loops k = 0..t.
// CL=true: gather float4 corners from channel-last images.
// CL=false: fallback, scalar gathers from original layout.
template <bool CL>
__global__ __launch_bounds__(256) void warp_pscan_v2(
    const float* __restrict__ cumT, const float* __restrict__ img,
    float* __restrict__ out) {
    int idx = blockIdx.x * blockDim.x + threadIdx.x;  // over 2*B*L*H*W
    if (idx >= 2 * BB * LL * HWL) return;
    int x  = idx & (WW - 1);
    int y  = (idx >> 6) & (HH - 1);
    int tl = (idx >> 12) & (LL - 1);
    int b  = (idx >> 17) & (BB - 1);
    int cg = idx >> 18;
    // Load-balance remap: pair t and 31-t across block-groups.
    int t = (tl < 16) ? tl : (47 - tl);
    int pix = y * WW + x;

    float gx = -1.0f + (float)(2 * x + 1) * (1.0f / WW);
    float gy = -1.0f + (float)(2 * y + 1) * (1.0f / HH);

    const float* cumP = cumT + ((size_t)b * HWL + pix) * LL * 2;
    float ctx = cumP[2 * t];
    float cty = cumP[2 * t + 1];

    float4 acc = make_float4(0.0f, 0.0f, 0.0f, 0.0f);

    for (int k2 = 0; k2 <= t; k2 += 2) {
        float4 c2 = *reinterpret_cast<const float4*>(cumP + 2 * k2);
#pragma unroll
        for (int s = 0; s < 2; ++s) {
            int k = k2 + s;
            if (k > t) continue;
            float dx = ctx - (s ? c2.z : c2.x);
            float dy = cty - (s ? c2.w : c2.y);
            float g0 = gx + dx;
            float g1 = gy + dy;
            // x wrap: jnp.remainder(g0 + 1, 2) - 1
            float m = fmodf(g0 + 1.0f, 2.0f);
            if (m < 0.0f) m += 2.0f;
            float gxw = m - 1.0f;
            float ix = ((gxw + 1.0f) * (float)WW - 1.0f) * 0.5f;
            float iy = ((g1 + 1.0f) * (float)HH - 1.0f) * 0.5f;
            float x0f = floorf(ix), y0f = floorf(iy);
            float wx1 = ix - x0f, wy1 = iy - y0f;
            float wx0 = 1.0f - wx1, wy0 = 1.0f - wy1;
            int x0 = (int)x0f, y0 = (int)y0f;
            int x1 = x0 + 1, y1 = y0 + 1;
            bool vx0 = (x0 >= 0) & (x0 < WW);
            bool vx1 = (x1 >= 0) & (x1 < WW);
            bool vy0 = (y0 >= 0) & (y0 < HH);
            bool vy1 = (y1 >= 0) & (y1 < HH);
            int x0c = min(max(x0, 0), WW - 1), x1c = min(max(x1, 0), WW - 1);
            int y0c = min(max(y0, 0), HH - 1), y1c = min(max(y1, 0), HH - 1);
            float w00 = (vx0 && vy0) ? wx0 * wy0 : 0.0f;
            float w10 = (vx1 && vy0) ? wx1 * wy0 : 0.0f;
            float w01 = (vx0 && vy1) ? wx0 * wy1 : 0.0f;
            float w11 = (vx1 && vy1) ? wx1 * wy1 : 0.0f;
            int o00 = y0c * WW + x0c, o10 = y0c * WW + x1c;
            int o01 = y1c * WW + x0c, o11 = y1c * WW + x1c;
            if (CL) {
                const float* ip =
                    img + (size_t)(b * LL + k) * HWL * CC + cg * 4;
                float4 v00 = *reinterpret_cast<const float4*>(ip + (size_t)o00 * CC);
                float4 v10 = *reinterpret_cast<const float4*>(ip + (size_t)o10 * CC);
                float4 v01 = *reinterpret_cast<const float4*>(ip + (size_t)o01 * CC);
                float4 v11 = *reinterpret_cast<const float4*>(ip + (size_t)o11 * CC);
                acc.x = fmaf(w00, v00.x, acc.x);
                acc.y = fmaf(w00, v00.y, acc.y);
                acc.z = fmaf(w00, v00.z, acc.z);
                acc.w = fmaf(w00, v00.w, acc.w);
                acc.x = fmaf(w10, v10.x, acc.x);
                acc.y = fmaf(w10, v10.y, acc.y);
                acc.z = fmaf(w10, v10.z, acc.z);
                acc.w = fmaf(w10, v10.w, acc.w);
                acc.x = fmaf(w01, v01.x, acc.x);
                acc.y = fmaf(w01, v01.y, acc.y);
                acc.z = fmaf(w01, v01.z, acc.z);
                acc.w = fmaf(w01, v01.w, acc.w);
                acc.x = fmaf(w11, v11.x, acc.x);
                acc.y = fmaf(w11, v11.y, acc.y);
                acc.z = fmaf(w11, v11.z, acc.z);
                acc.w = fmaf(w11, v11.w, acc.w);
            } else {
                const float* ip =
                    img + ((size_t)(b * LL + k) * CC + cg * 4) * HWL;
                float* a = &acc.x;
#pragma unroll
                for (int c = 0; c < 4; ++c) {
                    const float* ic = ip + (size_t)c * HWL;
                    a[c] += w00 * ic[o00] + w10 * ic[o10] + w01 * ic[o01] +
                            w11 * ic[o11];
                }
            }
        }
    }

    float* op = out + ((size_t)(b * LL + t) * CC + cg * 4) * HWL + pix;
    op[0]                = acc.x;
    op[(size_t)1 * HWL]  = acc.y;
    op[(size_t)2 * HWL]  = acc.z;
    op[(size_t)3 * HWL]  = acc.w;
}

extern "C" void kernel_launch(void* const* d_in, const int* in_sizes, int n_in,
                              void* d_out, int out_size, void* d_ws,
                              size_t ws_size, hipStream_t stream) {
    const float* flows  = (const float*)d_in[0];
    const float* images = (const float*)d_in[1];
    float* out = (float*)d_out;

    const size_t cum_bytes = (size_t)BB * HWL * LL * 2 * sizeof(float);  // 2 MiB
    const size_t img_bytes = (size_t)BB * LL * HWL * CC * sizeof(float); // 8 MiB
    float* cumT  = (float*)d_ws;
    float* imgcl = (float*)((char*)d_ws + cum_bytes);
    bool use_cl = (ws_size >= cum_bytes + img_bytes);

    int n1 = BB * HWL;
    cumsum_T_kernel<<<(n1 + 255) / 256, 256, 0, stream>>>(flows, cumT);

    int n3 = 2 * BB * LL * HWL;
    if (use_cl) {
        int n2 = BB * LL * HWL;
        repack_cl_kernel<<<(n2 + 255) / 256, 256, 0, stream>>>(images, imgcl);
        warp_pscan_v2<true><<<(n3 + 255) / 256, 256, 0, stream>>>(cumT, imgcl, out);
    } else {
        warp_pscan_v2<false><<<(n3 + 255) / 256, 256, 0, stream>>>(cumT, images, out);
    }
}

// Round 3
// 88.486 us; speedup vs baseline: 1.2547x; 1.1374x over previous
//
#include <hip/hip_runtime.h>

// Problem constants: B=2, L=32, C=8, H=W=64
#define BB 2
#define LL 32
#define CC 8
#define HH 64
#define WW 64
#define HWL 4096

// Kernel 1: cumsum of flows along L, stored TRANSPOSED as (b, pix, l, {x,y})
__global__ __launch_bounds__(256) void cumsum_T_kernel(
    const float* __restrict__ flows, float* __restrict__ cumT) {
    int idx = blockIdx.x * blockDim.x + threadIdx.x;  // over B*H*W = 8192
    if (idx >= BB * HWL) return;
    int pix = idx & (HWL - 1);
    int b   = idx >> 12;
    const float* f = flows + (size_t)b * LL * 2 * HWL + pix;
    float* o = cumT + ((size_t)b * HWL + pix) * LL * 2;
    float ax = 0.0f, ay = 0.0f;
    for (int l = 0; l < LL; ++l) {
        ax += f[(size_t)l * 2 * HWL];
        ay += f[(size_t)l * 2 * HWL + HWL];
        o[2 * l]     = ax;
        o[2 * l + 1] = ay;
    }
}

// Kernel 2: repack images (b,l,c,y,x) -> channel-group planes
// (b, l, cg, y, x, c4): pixel stride 16B inside a plane.
__global__ __launch_bounds__(256) void repack_cg_kernel(
    const float* __restrict__ img, float* __restrict__ imgp) {
    int idx = blockIdx.x * blockDim.x + threadIdx.x;  // over B*L*H*W = 262144
    if (idx >= BB * LL * HWL) return;
    int pix = idx & (HWL - 1);
    int bl  = idx >> 12;
    const float* ip = img + (size_t)bl * CC * HWL + pix;
    float4 lo, hi;
    lo.x = ip[0];
    lo.y = ip[(size_t)1 * HWL];
    lo.z = ip[(size_t)2 * HWL];
    lo.w = ip[(size_t)3 * HWL];
    hi.x = ip[(size_t)4 * HWL];
    hi.y = ip[(size_t)5 * HWL];
    hi.z = ip[(size_t)6 * HWL];
    hi.w = ip[(size_t)7 * HWL];
    float4* op = reinterpret_cast<float4*>(imgp);
    op[((size_t)bl * 2 + 0) * HWL + pix] = lo;
    op[((size_t)bl * 2 + 1) * HWL + pix] = hi;
}

// Bilinear sample of 4-channel plane pk at grid point (gx+dx, gy+dy),
// x wrapped. Math is bit-identical to the jnp reference (see notes).
__device__ __forceinline__ void sample4(const float4* __restrict__ pk,
                                        float gx, float gy, float ckx,
                                        float cky, float ctx, float cty,
                                        float4& acc) {
    float dx = ctx - ckx, dy = cty - cky;
    float g0 = gx + dx;
    float g1 = gy + dy;
    // remainder(g0+1, 2): a - 2*floor(a/2), exact (== fmodf path bitwise)
    float a = g0 + 1.0f;
    float h = a * 0.5f;
    float rem = (h - floorf(h)) * 2.0f;
    // ix = ((rem - 1 + 1)*64 - 1)*0.5 == rem*32 - 0.5 (exact)
    float ix = fmaf(rem, 32.0f, -0.5f);
    float b1 = g1 + 1.0f;
    float iy = fmaf(b1, 32.0f, -0.5f);  // == ((g1+1)*64 - 1)*0.5 (exact)
    float x0f = floorf(ix), y0f = floorf(iy);
    float wx1 = ix - x0f, wy1 = iy - y0f;
    float wx0 = 1.0f - wx1, wy0 = 1.0f - wy1;
    int x0 = (int)x0f, y0 = (int)y0f;  // x0 in [-1, 63] by wrap
    bool vx0 = x0 >= 0;
    bool vx1 = x0 < WW - 1;
    bool vy0 = (y0 >= 0) & (y0 < HH);
    bool vy1 = (y0 >= -1) & (y0 < HH - 1);
    int x0c = max(x0, 0), x1c = min(x0 + 1, WW - 1);
    int y0c = min(max(y0, 0), HH - 1), y1c = min(max(y0 + 1, 0), HH - 1);
    float w00 = (vx0 && vy0) ? wx0 * wy0 : 0.0f;
    float w10 = (vx1 && vy0) ? wx1 * wy0 : 0.0f;
    float w01 = (vx0 && vy1) ? wx0 * wy1 : 0.0f;
    float w11 = (vx1 && vy1) ? wx1 * wy1 : 0.0f;
    int r0 = y0c * WW, r1 = y1c * WW;
    float4 v00 = pk[r0 + x0c];
    float4 v10 = pk[r0 + x1c];
    float4 v01 = pk[r1 + x0c];
    float4 v11 = pk[r1 + x1c];
    acc.x = fmaf(w00, v00.x, acc.x);
    acc.y = fmaf(w00, v00.y, acc.y);
    acc.z = fmaf(w00, v00.z, acc.z);
    acc.w = fmaf(w00, v00.w, acc.w);
    acc.x = fmaf(w10, v10.x, acc.x);
    acc.y = fmaf(w10, v10.y, acc.y);
    acc.z = fmaf(w10, v10.z, acc.z);
    acc.w = fmaf(w10, v10.w, acc.w);
    acc.x = fmaf(w01, v01.x, acc.x);
    acc.y = fmaf(w01, v01.y, acc.y);
    acc.z = fmaf(w01, v01.z, acc.z);
    acc.w = fmaf(w01, v01.w, acc.w);
    acc.x = fmaf(w11, v11.x, acc.x);
    acc.y = fmaf(w11, v11.y, acc.y);
    acc.z = fmaf(w11, v11.z, acc.z);
    acc.w = fmaf(w11, v11.w, acc.w);
}

// Kernel 3: thread = (cg, b, tl, y, x), tl in [0,16). Handles t_lo = tl and
// t_hi = 31 - tl: exactly 33 samples per thread (uniform work), shared cum_k
// loads, 8 outstanding gathers per joint k-step.
__global__ __launch_bounds__(256) void warp_pscan_v3(
    const float* __restrict__ cumT, const float* __restrict__ imgp,
    float* __restrict__ out) {
    int idx = blockIdx.x * blockDim.x + threadIdx.x;  // over 2*2*16*4096
    if (idx >= 2 * BB * (LL / 2) * HWL) return;
    int x  = idx & (WW - 1);
    int y  = (idx >> 6) & (HH - 1);
    int tl = (idx >> 12) & 15;
    int b  = (idx >> 16) & 1;
    int cg = idx >> 17;
    int t_lo = tl, t_hi = (LL - 1) - tl;
    int pix = y * WW + x;

    float gx = -1.0f + (float)(2 * x + 1) * (1.0f / WW);
    float gy = -1.0f + (float)(2 * y + 1) * (1.0f / HH);

    const float* cumP = cumT + ((size_t)b * HWL + pix) * LL * 2;
    float2 clo = *reinterpret_cast<const float2*>(cumP + 2 * t_lo);
    float2 chi = *reinterpret_cast<const float2*>(cumP + 2 * t_hi);

    float4 acc_lo = make_float4(0.0f, 0.0f, 0.0f, 0.0f);
    float4 acc_hi = make_float4(0.0f, 0.0f, 0.0f, 0.0f);

    const float4* planes = reinterpret_cast<const float4*>(imgp);
    float2 ck = *reinterpret_cast<const float2*>(cumP);  // k = 0

#pragma unroll 2
    for (int k = 0; k <= t_hi; ++k) {
        float2 cn = ck;
        if (k < t_hi) cn = *reinterpret_cast<const float2*>(cumP + 2 * (k + 1));
        const float4* pk = planes + ((size_t)((b * LL + k) * 2) + cg) * HWL;
        if (k <= t_lo)
            sample4(pk, gx, gy, ck.x, ck.y, clo.x, clo.y, acc_lo);
        sample4(pk, gx, gy, ck.x, ck.y, chi.x, chi.y, acc_hi);
        ck = cn;
    }

    float* olo = out + ((size_t)((b * LL + t_lo) * CC) + cg * 4) * HWL + pix;
    olo[0]               = acc_lo.x;
    olo[(size_t)1 * HWL] = acc_lo.y;
    olo[(size_t)2 * HWL] = acc_lo.z;
    olo[(size_t)3 * HWL] = acc_lo.w;
    float* ohi = out + ((size_t)((b * LL + t_hi) * CC) + cg * 4) * HWL + pix;
    ohi[0]               = acc_hi.x;
    ohi[(size_t)1 * HWL] = acc_hi.y;
    ohi[(size_t)2 * HWL] = acc_hi.z;
    ohi[(size_t)3 * HWL] = acc_hi.w;
}

// Fallback (ws too small): round-1-style kernel on original layouts.
__global__ __launch_bounds__(256) void warp_pscan_fb(
    const float* __restrict__ cumT, const float* __restrict__ images,
    float* __restrict__ out) {
    int idx = blockIdx.x * blockDim.x + threadIdx.x;
    if (idx >= BB * LL * HWL) return;
    int x  = idx & (WW - 1);
    int y  = (idx >> 6) & (HH - 1);
    int tl = (idx >> 12) & (LL - 1);
    int b  = idx >> 17;
    int t = (tl < 16) ? tl : (47 - tl);
    int pix = y * WW + x;
    float gx = -1.0f + (float)(2 * x + 1) * (1.0f / WW);
    float gy = -1.0f + (float)(2 * y + 1) * (1.0f / HH);
    const float* cumP = cumT + ((size_t)b * HWL + pix) * LL * 2;
    float ctx = cumP[2 * t], cty = cumP[2 * t + 1];
    float acc[CC];
#pragma unroll
    for (int c = 0; c < CC; ++c) acc[c] = 0.0f;
    const float* imgb = images + (size_t)b * LL * CC * HWL;
    for (int k = 0; k <= t; ++k) {
        float dx = ctx - cumP[2 * k];
        float dy = cty - cumP[2 * k + 1];
        float g0 = gx + dx, g1 = gy + dy;
        float a = g0 + 1.0f, h = a * 0.5f;
        float rem = (h - floorf(h)) * 2.0f;
        float ix = fmaf(rem, 32.0f, -0.5f);
        float iy = fmaf(g1 + 1.0f, 32.0f, -0.5f);
        float x0f = floorf(ix), y0f = floorf(iy);
        float wx1 = ix - x0f, wy1 = iy - y0f;
        float wx0 = 1.0f - wx1, wy0 = 1.0f - wy1;
        int x0 = (int)x0f, y0 = (int)y0f;
        bool vx0 = x0 >= 0, vx1 = x0 < WW - 1;
        bool vy0 = (y0 >= 0) & (y0 < HH), vy1 = (y0 >= -1) & (y0 < HH - 1);
        int x0c = max(x0, 0), x1c = min(x0 + 1, WW - 1);
        int y0c = min(max(y0, 0), HH - 1), y1c = min(max(y0 + 1, 0), HH - 1);
        float w00 = (vx0 && vy0) ? wx0 * wy0 : 0.0f;
        float w10 = (vx1 && vy0) ? wx1 * wy0 : 0.0f;
        float w01 = (vx0 && vy1) ? wx0 * wy1 : 0.0f;
        float w11 = (vx1 && vy1) ? wx1 * wy1 : 0.0f;
        int o00 = y0c * WW + x0c, o10 = y0c * WW + x1c;
        int o01 = y1c * WW + x0c, o11 = y1c * WW + x1c;
        const float* ip = imgb + (size_t)k * CC * HWL;
#pragma unroll
        for (int c = 0; c < CC; ++c) {
            const float* ic = ip + (size_t)c * HWL;
            acc[c] += w00 * ic[o00] + w10 * ic[o10] + w01 * ic[o01] +
                      w11 * ic[o11];
        }
    }
    float* op = out + ((size_t)(b * LL + t) * CC) * HWL + pix;
#pragma unroll
    for (int c = 0; c < CC; ++c) op[(size_t)c * HWL] = acc[c];
}

extern "C" void kernel_launch(void* const* d_in, const int* in_sizes, int n_in,
                              void* d_out, int out_size, void* d_ws,
                              size_t ws_size, hipStream_t stream) {
    const float* flows  = (const float*)d_in[0];
    const float* images = (const float*)d_in[1];
    float* out = (float*)d_out;

    const size_t cum_bytes = (size_t)BB * HWL * LL * 2 * sizeof(float);  // 2 MiB
    const size_t img_bytes = (size_t)BB * LL * HWL * CC * sizeof(float); // 8 MiB
    float* cumT = (float*)d_ws;
    float* imgp = (float*)((char*)d_ws + cum_bytes);
    bool packed = (ws_size >= cum_bytes + img_bytes);

    int n1 = BB * HWL;
    cumsum_T_kernel<<<(n1 + 255) / 256, 256, 0, stream>>>(flows, cumT);

    if (packed) {
        int n2 = BB * LL * HWL;
        repack_cg_kernel<<<(n2 + 255) / 256, 256, 0, stream>>>(images, imgp);
        int n3 = 2 * BB * (LL / 2) * HWL;
        warp_pscan_v3<<<(n3 + 255) / 256, 256, 0, stream>>>(cumT, imgp, out);
    } else {
        int n3 = BB * LL * HWL;
        warp_pscan_fb<<<(n3 + 255) / 256, 256, 0, stream>>>(cumT, images, out);
    }
}

// Round 4
// 82.910 us; speedup vs baseline: 1.3391x; 1.0673x over previous
//
#include <hip/hip_runtime.h>

// Problem constants: B=2, L=32, C=8, H=W=64
#define BB 2
#define LL 32
#define CC 8
#define HH 64
#define WW 64
#define HWL 4096

// Kernel 1: cumsum of flows along L, stored TRANSPOSED as (b, pix, l, {x,y})
__global__ __launch_bounds__(256) void cumsum_T_kernel(
    const float* __restrict__ flows, float* __restrict__ cumT) {
    int idx = blockIdx.x * blockDim.x + threadIdx.x;  // over B*H*W = 8192
    if (idx >= BB * HWL) return;
    int pix = idx & (HWL - 1);
    int b   = idx >> 12;
    const float* f = flows + (size_t)b * LL * 2 * HWL + pix;
    float* o = cumT + ((size_t)b * HWL + pix) * LL * 2;
    float ax = 0.0f, ay = 0.0f;
    for (int l = 0; l < LL; ++l) {
        ax += f[(size_t)l * 2 * HWL];
        ay += f[(size_t)l * 2 * HWL + HWL];
        o[2 * l]     = ax;
        o[2 * l + 1] = ay;
    }
}

// Kernel 2: repack images (b,l,c,y,x) -> channel-group planes
// (b, l, cg, y, x, c4): pixel stride 16B inside a plane.
__global__ __launch_bounds__(256) void repack_cg_kernel(
    const float* __restrict__ img, float* __restrict__ imgp) {
    int idx = blockIdx.x * blockDim.x + threadIdx.x;  // over B*L*H*W = 262144
    if (idx >= BB * LL * HWL) return;
    int pix = idx & (HWL - 1);
    int bl  = idx >> 12;
    const float* ip = img + (size_t)bl * CC * HWL + pix;
    float4 lo, hi;
    lo.x = ip[0];
    lo.y = ip[(size_t)1 * HWL];
    lo.z = ip[(size_t)2 * HWL];
    lo.w = ip[(size_t)3 * HWL];
    hi.x = ip[(size_t)4 * HWL];
    hi.y = ip[(size_t)5 * HWL];
    hi.z = ip[(size_t)6 * HWL];
    hi.w = ip[(size_t)7 * HWL];
    float4* op = reinterpret_cast<float4*>(imgp);
    op[((size_t)bl * 2 + 0) * HWL + pix] = lo;
    op[((size_t)bl * 2 + 1) * HWL + pix] = hi;
}

// Bilinear sample of 4-channel plane pk at (gx+dx, gy+dy), x wrapped.
// Bit-identical to the jnp reference path.
__device__ __forceinline__ void sample4(const float4* __restrict__ pk,
                                        float gx, float gy, float ckx,
                                        float cky, float ctx, float cty,
                                        float4& acc) {
    float dx = ctx - ckx, dy = cty - cky;
    float g0 = gx + dx;
    float g1 = gy + dy;
    float a = g0 + 1.0f;
    float h = a * 0.5f;
    float rem = (h - floorf(h)) * 2.0f;       // remainder(g0+1, 2), exact
    float ix = fmaf(rem, 32.0f, -0.5f);       // ((rem)*64 - 1)*0.5, exact
    float iy = fmaf(g1 + 1.0f, 32.0f, -0.5f); // ((g1+1)*64 - 1)*0.5, exact
    float x0f = floorf(ix), y0f = floorf(iy);
    float wx1 = ix - x0f, wy1 = iy - y0f;
    float wx0 = 1.0f - wx1, wy0 = 1.0f - wy1;
    int x0 = (int)x0f, y0 = (int)y0f;  // x0 in [-1, 63] after wrap
    bool vx0 = x0 >= 0;
    bool vx1 = x0 < WW - 1;
    bool vy0 = (y0 >= 0) & (y0 < HH);
    bool vy1 = (y0 >= -1) & (y0 < HH - 1);
    int x0c = max(x0, 0), x1c = min(x0 + 1, WW - 1);
    int y0c = min(max(y0, 0), HH - 1), y1c = min(max(y0 + 1, 0), HH - 1);
    float w00 = (vx0 && vy0) ? wx0 * wy0 : 0.0f;
    float w10 = (vx1 && vy0) ? wx1 * wy0 : 0.0f;
    float w01 = (vx0 && vy1) ? wx0 * wy1 : 0.0f;
    float w11 = (vx1 && vy1) ? wx1 * wy1 : 0.0f;
    int r0 = y0c * WW, r1 = y1c * WW;
    float4 v00 = pk[r0 + x0c];
    float4 v10 = pk[r0 + x1c];
    float4 v01 = pk[r1 + x0c];
    float4 v11 = pk[r1 + x1c];
    acc.x = fmaf(w00, v00.x, acc.x);
    acc.y = fmaf(w00, v00.y, acc.y);
    acc.z = fmaf(w00, v00.z, acc.z);
    acc.w = fmaf(w00, v00.w, acc.w);
    acc.x = fmaf(w10, v10.x, acc.x);
    acc.y = fmaf(w10, v10.y, acc.y);
    acc.z = fmaf(w10, v10.z, acc.z);
    acc.w = fmaf(w10, v10.w, acc.w);
    acc.x = fmaf(w01, v01.x, acc.x);
    acc.y = fmaf(w01, v01.y, acc.y);
    acc.z = fmaf(w01, v01.z, acc.z);
    acc.w = fmaf(w01, v01.w, acc.w);
    acc.x = fmaf(w11, v11.x, acc.x);
    acc.y = fmaf(w11, v11.y, acc.y);
    acc.z = fmaf(w11, v11.z, acc.z);
    acc.w = fmaf(w11, v11.w, acc.w);
}

// Kernel 3: thread = (kh, cg, b, tl, y, x). Handles t_lo = tl, t_hi = 31-tl
// for HALF the k-range (split at K0 so every thread does 16 or 17 samples).
// kh=1 writes `out`, kh=0 writes `part`; add_partial combines.
__global__ __launch_bounds__(256) void warp_pscan_v4(
    const float* __restrict__ cumT, const float* __restrict__ imgp,
    float* __restrict__ part, float* __restrict__ out) {
    int idx = blockIdx.x * blockDim.x + threadIdx.x;  // 2*2*2*16*4096
    if (idx >= 2 * 2 * BB * (LL / 2) * HWL) return;
    int x  = idx & (WW - 1);
    int y  = (idx >> 6) & (HH - 1);
    int tl = (idx >> 12) & 15;
    int b  = (idx >> 16) & 1;
    int cg = (idx >> 17) & 1;
    int kh = (idx >> 18) & 1;
    int t_lo = tl, t_hi = (LL - 1) - tl;
    // Split point: samples(k) = 2 for k<=t_lo else 1; K0 puts 16 in half 0.
    int K0 = (tl >= 7) ? 8 : (15 - tl);
    int kb = kh ? K0 : 0;
    int ke = kh ? t_hi : (K0 - 1);  // inclusive
    int pix = y * WW + x;

    float gx = -1.0f + (float)(2 * x + 1) * (1.0f / WW);
    float gy = -1.0f + (float)(2 * y + 1) * (1.0f / HH);

    const float* cumP = cumT + ((size_t)b * HWL + pix) * LL * 2;
    float2 clo = *reinterpret_cast<const float2*>(cumP + 2 * t_lo);
    float2 chi = *reinterpret_cast<const float2*>(cumP + 2 * t_hi);

    float4 acc_lo = make_float4(0.0f, 0.0f, 0.0f, 0.0f);
    float4 acc_hi = make_float4(0.0f, 0.0f, 0.0f, 0.0f);

    const float4* planes = reinterpret_cast<const float4*>(imgp);
    float2 ck = *reinterpret_cast<const float2*>(cumP + 2 * kb);

#pragma unroll 2
    for (int k = kb; k <= ke; ++k) {
        float2 cn = ck;
        if (k < ke) cn = *reinterpret_cast<const float2*>(cumP + 2 * (k + 1));
        const float4* pk = planes + ((size_t)((b * LL + k) * 2) + cg) * HWL;
        if (k <= t_lo)
            sample4(pk, gx, gy, ck.x, ck.y, clo.x, clo.y, acc_lo);
        sample4(pk, gx, gy, ck.x, ck.y, chi.x, chi.y, acc_hi);
        ck = cn;
    }

    float* po = kh ? out : part;
    float* olo = po + ((size_t)((b * LL + t_lo) * CC) + cg * 4) * HWL + pix;
    olo[0]               = acc_lo.x;
    olo[(size_t)1 * HWL] = acc_lo.y;
    olo[(size_t)2 * HWL] = acc_lo.z;
    olo[(size_t)3 * HWL] = acc_lo.w;
    float* ohi = po + ((size_t)((b * LL + t_hi) * CC) + cg * 4) * HWL + pix;
    ohi[0]               = acc_hi.x;
    ohi[(size_t)1 * HWL] = acc_hi.y;
    ohi[(size_t)2 * HWL] = acc_hi.z;
    ohi[(size_t)3 * HWL] = acc_hi.w;
}

// Kernel 4: out += part, vectorized float4.
__global__ __launch_bounds__(256) void add_partial_kernel(
    const float* __restrict__ part, float* __restrict__ out) {
    int i = blockIdx.x * blockDim.x + threadIdx.x;  // over 2M/4 = 524288
    if (i >= BB * LL * CC * HWL / 4) return;
    const float4* p4 = reinterpret_cast<const float4*>(part);
    float4* o4 = reinterpret_cast<float4*>(out);
    float4 a = o4[i], p = p4[i];
    a.x += p.x;
    a.y += p.y;
    a.z += p.z;
    a.w += p.w;
    o4[i] = a;
}

// Fallback paths ------------------------------------------------------------
// v3 (packed, no k-split) used if ws fits cum+img only.
__global__ __launch_bounds__(256) void warp_pscan_v3(
    const float* __restrict__ cumT, const float* __restrict__ imgp,
    float* __restrict__ out) {
    int idx = blockIdx.x * blockDim.x + threadIdx.x;
    if (idx >= 2 * BB * (LL / 2) * HWL) return;
    int x  = idx & (WW - 1);
    int y  = (idx >> 6) & (HH - 1);
    int tl = (idx >> 12) & 15;
    int b  = (idx >> 16) & 1;
    int cg = idx >> 17;
    int t_lo = tl, t_hi = (LL - 1) - tl;
    int pix = y * WW + x;
    float gx = -1.0f + (float)(2 * x + 1) * (1.0f / WW);
    float gy = -1.0f + (float)(2 * y + 1) * (1.0f / HH);
    const float* cumP = cumT + ((size_t)b * HWL + pix) * LL * 2;
    float2 clo = *reinterpret_cast<const float2*>(cumP + 2 * t_lo);
    float2 chi = *reinterpret_cast<const float2*>(cumP + 2 * t_hi);
    float4 acc_lo = make_float4(0.0f, 0.0f, 0.0f, 0.0f);
    float4 acc_hi = make_float4(0.0f, 0.0f, 0.0f, 0.0f);
    const float4* planes = reinterpret_cast<const float4*>(imgp);
    float2 ck = *reinterpret_cast<const float2*>(cumP);
#pragma unroll 2
    for (int k = 0; k <= t_hi; ++k) {
        float2 cn = ck;
        if (k < t_hi) cn = *reinterpret_cast<const float2*>(cumP + 2 * (k + 1));
        const float4* pk = planes + ((size_t)((b * LL + k) * 2) + cg) * HWL;
        if (k <= t_lo)
            sample4(pk, gx, gy, ck.x, ck.y, clo.x, clo.y, acc_lo);
        sample4(pk, gx, gy, ck.x, ck.y, chi.x, chi.y, acc_hi);
        ck = cn;
    }
    float* olo = out + ((size_t)((b * LL + t_lo) * CC) + cg * 4) * HWL + pix;
    olo[0]               = acc_lo.x;
    olo[(size_t)1 * HWL] = acc_lo.y;
    olo[(size_t)2 * HWL] = acc_lo.z;
    olo[(size_t)3 * HWL] = acc_lo.w;
    float* ohi = out + ((size_t)((b * LL + t_hi) * CC) + cg * 4) * HWL + pix;
    ohi[0]               = acc_hi.x;
    ohi[(size_t)1 * HWL] = acc_hi.y;
    ohi[(size_t)2 * HWL] = acc_hi.z;
    ohi[(size_t)3 * HWL] = acc_hi.w;
}

__global__ __launch_bounds__(256) void warp_pscan_fb(
    const float* __restrict__ cumT, const float* __restrict__ images,
    float* __restrict__ out) {
    int idx = blockIdx.x * blockDim.x + threadIdx.x;
    if (idx >= BB * LL * HWL) return;
    int x  = idx & (WW - 1);
    int y  = (idx >> 6) & (HH - 1);
    int tl = (idx >> 12) & (LL - 1);
    int b  = idx >> 17;
    int t = (tl < 16) ? tl : (47 - tl);
    int pix = y * WW + x;
    float gx = -1.0f + (float)(2 * x + 1) * (1.0f / WW);
    float gy = -1.0f + (float)(2 * y + 1) * (1.0f / HH);
    const float* cumP = cumT + ((size_t)b * HWL + pix) * LL * 2;
    float ctx = cumP[2 * t], cty = cumP[2 * t + 1];
    float acc[CC];
#pragma unroll
    for (int c = 0; c < CC; ++c) acc[c] = 0.0f;
    const float* imgb = images + (size_t)b * LL * CC * HWL;
    for (int k = 0; k <= t; ++k) {
        float dx = ctx - cumP[2 * k];
        float dy = cty - cumP[2 * k + 1];
        float g0 = gx + dx, g1 = gy + dy;
        float a = g0 + 1.0f, h = a * 0.5f;
        float rem = (h - floorf(h)) * 2.0f;
        float ix = fmaf(rem, 32.0f, -0.5f);
        float iy = fmaf(g1 + 1.0f, 32.0f, -0.5f);
        float x0f = floorf(ix), y0f = floorf(iy);
        float wx1 = ix - x0f, wy1 = iy - y0f;
        float wx0 = 1.0f - wx1, wy0 = 1.0f - wy1;
        int x0 = (int)x0f, y0 = (int)y0f;
        bool vx0 = x0 >= 0, vx1 = x0 < WW - 1;
        bool vy0 = (y0 >= 0) & (y0 < HH), vy1 = (y0 >= -1) & (y0 < HH - 1);
        int x0c = max(x0, 0), x1c = min(x0 + 1, WW - 1);
        int y0c = min(max(y0, 0), HH - 1), y1c = min(max(y0 + 1, 0), HH - 1);
        float w00 = (vx0 && vy0) ? wx0 * wy0 : 0.0f;
        float w10 = (vx1 && vy0) ? wx1 * wy0 : 0.0f;
        float w01 = (vx0 && vy1) ? wx0 * wy1 : 0.0f;
        float w11 = (vx1 && vy1) ? wx1 * wy1 : 0.0f;
        int o00 = y0c * WW + x0c, o10 = y0c * WW + x1c;
        int o01 = y1c * WW + x0c, o11 = y1c * WW + x1c;
        const float* ip = imgb + (size_t)k * CC * HWL;
#pragma unroll
        for (int c = 0; c < CC; ++c) {
            const float* ic = ip + (size_t)c * HWL;
            acc[c] += w00 * ic[o00] + w10 * ic[o10] + w01 * ic[o01] +
                      w11 * ic[o11];
        }
    }
    float* op = out + ((size_t)(b * LL + t) * CC) * HWL + pix;
#pragma unroll
    for (int c = 0; c < CC; ++c) op[(size_t)c * HWL] = acc[c];
}

extern "C" void kernel_launch(void* const* d_in, const int* in_sizes, int n_in,
                              void* d_out, int out_size, void* d_ws,
                              size_t ws_size, hipStream_t stream) {
    const float* flows  = (const float*)d_in[0];
    const float* images = (const float*)d_in[1];
    float* out = (float*)d_out;

    const size_t cum_bytes  = (size_t)BB * HWL * LL * 2 * sizeof(float); // 2 MiB
    const size_t img_bytes  = (size_t)BB * LL * HWL * CC * sizeof(float); // 8 MiB
    const size_t part_bytes = (size_t)BB * LL * CC * HWL * sizeof(float); // 8 MiB
    float* cumT = (float*)d_ws;
    float* imgp = (float*)((char*)d_ws + cum_bytes);
    float* part = (float*)((char*)d_ws + cum_bytes + img_bytes);
    bool packed = (ws_size >= cum_bytes + img_bytes);
    bool split  = (ws_size >= cum_bytes + img_bytes + part_bytes);

    int n1 = BB * HWL;
    cumsum_T_kernel<<<(n1 + 255) / 256, 256, 0, stream>>>(flows, cumT);

    if (packed) {
        int n2 = BB * LL * HWL;
        repack_cg_kernel<<<(n2 + 255) / 256, 256, 0, stream>>>(images, imgp);
        if (split) {
            int n3 = 2 * 2 * BB * (LL / 2) * HWL;
            warp_pscan_v4<<<(n3 + 255) / 256, 256, 0, stream>>>(cumT, imgp,
                                                                part, out);
            int n4 = BB * LL * CC * HWL / 4;
            add_partial_kernel<<<(n4 + 255) / 256, 256, 0, stream>>>(part, out);
        } else {
            int n3 = 2 * BB * (LL / 2) * HWL;
            warp_pscan_v3<<<(n3 + 255) / 256, 256, 0, stream>>>(cumT, imgp, out);
        }
    } else {
        int n3 = BB * LL * HWL;
        warp_pscan_fb<<<(n3 + 255) / 256, 256, 0, stream>>>(cumT, images, out);
    }
}

// Round 5
// 58.471 us; speedup vs baseline: 1.8987x; 1.4180x over previous
//
#include <hip/hip_runtime.h>

// Problem constants: B=2, L=32, C=8, H=W=64
#define BB 2
#define LL 32
#define CC 8
#define HH 64
#define WW 64
#define HWL 4096

typedef _Float16 h2 __attribute__((ext_vector_type(2)));

#if defined(__has_builtin)
#if __has_builtin(__builtin_amdgcn_fdot2)
#define HAVE_FDOT2 1
#endif
#endif

__device__ __forceinline__ float fdot2f(h2 a, h2 b, float c) {
#ifdef HAVE_FDOT2
    return __builtin_amdgcn_fdot2(a, b, c, false);
#else
    return c + (float)a.x * (float)b.x + (float)a.y * (float)b.y;
#endif
}

__device__ __forceinline__ h2 f2h2(float lo, float hi) {
    h2 r;
    r.x = (_Float16)lo;
    r.y = (_Float16)hi;
    return r;
}

__device__ __forceinline__ h2 asf_h2(float f) {
    union { float f; h2 h; } u;
    u.f = f;
    return u.h;
}

__device__ __forceinline__ float ash_f(h2 h) {
    union { float f; h2 h; } u;
    u.h = h;
    return u.f;
}

// Kernel 1: cumsum of flows along L, STANDARD layout (b, l, 2, h, w) —
// per-k loads in the main kernel are then lane-coalesced (9 line-touches
// per wave-instr instead of 64 with the transposed layout).
__global__ __launch_bounds__(256) void cumsum_kernel(
    const float* __restrict__ flows, float* __restrict__ cum) {
    int idx = blockIdx.x * blockDim.x + threadIdx.x;  // over B*2*H*W = 32768
    if (idx >= BB * 2 * HWL) return;
    int pix  = idx & (HWL - 1);
    int rest = idx >> 12;  // b*2 + comp
    int comp = rest & 1;
    int b    = rest >> 1;
    size_t base = ((size_t)(b * LL) * 2 + comp) * HWL + pix;
    float acc = 0.0f;
    for (int l = 0; l < LL; ++l) {
        acc += flows[base + (size_t)l * 2 * HWL];
        cum[base + (size_t)l * 2 * HWL] = acc;
    }
}

// Kernel 2: repack images to fp16 parity pair-records.
// Per (b,l,cg) plane: float4 rec[y][par][32], rec = 4 half2 words,
// word c = (px_a.ch, px_b.ch) where px_a = 2*rec+par, px_b = px_a+1
// (px_b==64 -> 0 pad). 16B-aligned gathers covering both x corners + 4 ch.
__global__ __launch_bounds__(256) void repack_h2_kernel(
    const float* __restrict__ img, float* __restrict__ planes) {
    int idx = blockIdx.x * blockDim.x + threadIdx.x;  // over 2*32*64*32
    if (idx >= BB * LL * HH * 32) return;
    int rec = idx & 31;
    int y   = (idx >> 5) & 63;
    int bl  = idx >> 11;  // b*32 + l
    const float* ip = img + (size_t)bl * CC * HWL + y * WW + 2 * rec;
    bool last = (rec == 31);
    float a0[8], a1[8], bx[8];
#pragma unroll
    for (int c = 0; c < 8; ++c) {
        float2 A = *reinterpret_cast<const float2*>(ip + (size_t)c * HWL);
        a0[c] = A.x;
        a1[c] = A.y;
        float Bv = 0.0f;
        if (!last) Bv = ip[(size_t)c * HWL + 2];
        bx[c] = Bv;
    }
    float4 evA, evB, odA, odB;
    evA.x = ash_f(f2h2(a0[0], a1[0]));
    evA.y = ash_f(f2h2(a0[1], a1[1]));
    evA.z = ash_f(f2h2(a0[2], a1[2]));
    evA.w = ash_f(f2h2(a0[3], a1[3]));
    evB.x = ash_f(f2h2(a0[4], a1[4]));
    evB.y = ash_f(f2h2(a0[5], a1[5]));
    evB.z = ash_f(f2h2(a0[6], a1[6]));
    evB.w = ash_f(f2h2(a0[7], a1[7]));
    odA.x = ash_f(f2h2(a1[0], bx[0]));
    odA.y = ash_f(f2h2(a1[1], bx[1]));
    odA.z = ash_f(f2h2(a1[2], bx[2]));
    odA.w = ash_f(f2h2(a1[3], bx[3]));
    odB.x = ash_f(f2h2(a1[4], bx[4]));
    odB.y = ash_f(f2h2(a1[5], bx[5]));
    odB.z = ash_f(f2h2(a1[6], bx[6]));
    odB.w = ash_f(f2h2(a1[7], bx[7]));
    float4* P = reinterpret_cast<float4*>(planes);
    size_t base0 = ((size_t)bl * 2 + 0) * 4096 + (size_t)y * 64;
    size_t base1 = ((size_t)bl * 2 + 1) * 4096 + (size_t)y * 64;
    P[base0 + rec]      = evA;  // par 0 (even x0), cg0
    P[base0 + 32 + rec] = odA;  // par 1 (odd x0),  cg0
    P[base1 + rec]      = evB;
    P[base1 + 32 + rec] = odB;
}

// Bilinear sample of a 4-ch fp16 parity-record plane. Grid math identical
// to rounds 3/4 (bit-exact wrap); values/weights quantized to fp16.
__device__ __forceinline__ void sampleH(const float4* __restrict__ pk,
                                        float gx, float gy, float ckx,
                                        float cky, float ctx, float cty,
                                        float4& acc) {
    float dx = ctx - ckx, dy = cty - cky;
    float g0 = gx + dx;
    float g1 = gy + dy;
    float a = g0 + 1.0f;
    float h = a * 0.5f;
    float rem = (h - floorf(h)) * 2.0f;        // remainder(g0+1, 2), exact
    float ix = fmaf(rem, 32.0f, -0.5f);
    float iy = fmaf(g1 + 1.0f, 32.0f, -0.5f);
    float x0f = floorf(ix), y0f = floorf(iy);
    float wx1 = ix - x0f, wy1 = iy - y0f;
    float wx0 = 1.0f - wx1, wy0 = 1.0f - wy1;
    int x0 = (int)x0f, y0 = (int)y0f;  // x0 in [-1,63] after wrap
    bool vx0 = x0 >= 0;
    bool vx1 = x0 < WW - 1;
    bool vy0 = (y0 >= 0) & (y0 < HH);
    bool vy1 = (y0 >= -1) & (y0 < HH - 1);
    float w00 = (vx0 && vy0) ? wx0 * wy0 : 0.0f;
    float w10 = (vx1 && vy0) ? wx1 * wy0 : 0.0f;
    float w01 = (vx0 && vy1) ? wx0 * wy1 : 0.0f;
    float w11 = (vx1 && vy1) ? wx1 * wy1 : 0.0f;
    // x0=-1: record at xa=0 holds (px0,px1); v10 lives in slot 0.
    int xa = max(x0, 0);
    bool lo1 = x0 < 0;
    float wA = lo1 ? w10 : w00;
    float wB = lo1 ? 0.0f : w10;
    float wC = lo1 ? w11 : w01;
    float wD = lo1 ? 0.0f : w11;
    int y0c = min(max(y0, 0), HH - 1), y1c = min(max(y0 + 1, 0), HH - 1);
    int xoff = ((xa & 1) << 5) + (xa >> 1);
    float4 r0 = pk[y0c * 64 + xoff];
    float4 r1 = pk[y1c * 64 + xoff];
    h2 hAB = f2h2(wA, wB);
    h2 hCD = f2h2(wC, wD);
    acc.x = fdot2f(asf_h2(r0.x), hAB, acc.x);
    acc.y = fdot2f(asf_h2(r0.y), hAB, acc.y);
    acc.z = fdot2f(asf_h2(r0.z), hAB, acc.z);
    acc.w = fdot2f(asf_h2(r0.w), hAB, acc.w);
    acc.x = fdot2f(asf_h2(r1.x), hCD, acc.x);
    acc.y = fdot2f(asf_h2(r1.y), hCD, acc.y);
    acc.z = fdot2f(asf_h2(r1.z), hCD, acc.z);
    acc.w = fdot2f(asf_h2(r1.w), hCD, acc.w);
}

// Kernel 3: thread = (kh, cg, b, tl, y, x); t-pair + k-half split (v4
// balance), fp16 record gathers, coalesced cum loads.
__global__ __launch_bounds__(256) void warp_pscan_v5(
    const float* __restrict__ cum, const float* __restrict__ planes,
    float* __restrict__ part, float* __restrict__ out) {
    int idx = blockIdx.x * blockDim.x + threadIdx.x;  // 2*2*2*16*4096
    if (idx >= 2 * 2 * BB * (LL / 2) * HWL) return;
    int x  = idx & (WW - 1);
    int y  = (idx >> 6) & (HH - 1);
    int tl = (idx >> 12) & 15;
    int b  = (idx >> 16) & 1;
    int cg = (idx >> 17) & 1;
    int kh = (idx >> 18) & 1;
    int t_lo = tl, t_hi = (LL - 1) - tl;
    int K0 = (tl >= 7) ? 8 : (15 - tl);
    int kb = kh ? K0 : 0;
    int ke = kh ? t_hi : (K0 - 1);  // inclusive
    int pix = y * WW + x;

    float gx = -1.0f + (float)(2 * x + 1) * (1.0f / WW);
    float gy = -1.0f + (float)(2 * y + 1) * (1.0f / HH);

    const float* cumb = cum + (size_t)b * LL * 2 * HWL + pix;
    float ctxlo = cumb[(size_t)(2 * t_lo) * HWL];
    float ctylo = cumb[(size_t)(2 * t_lo + 1) * HWL];
    float ctxhi = cumb[(size_t)(2 * t_hi) * HWL];
    float ctyhi = cumb[(size_t)(2 * t_hi + 1) * HWL];

    float4 acc_lo = make_float4(0.0f, 0.0f, 0.0f, 0.0f);
    float4 acc_hi = make_float4(0.0f, 0.0f, 0.0f, 0.0f);

    const float4* pl = reinterpret_cast<const float4*>(planes);

#pragma unroll 2
    for (int k = kb; k <= ke; ++k) {
        float ckx = cumb[(size_t)(2 * k) * HWL];
        float cky = cumb[(size_t)(2 * k + 1) * HWL];
        const float4* pk = pl + ((size_t)((b * LL + k) * 2) + cg) * 4096;
        if (k <= t_lo)
            sampleH(pk, gx, gy, ckx, cky, ctxlo, ctylo, acc_lo);
        sampleH(pk, gx, gy, ckx, cky, ctxhi, ctyhi, acc_hi);
    }

    float* po = kh ? out : part;
    float* olo = po + ((size_t)((b * LL + t_lo) * CC) + cg * 4) * HWL + pix;
    olo[0]               = acc_lo.x;
    olo[(size_t)1 * HWL] = acc_lo.y;
    olo[(size_t)2 * HWL] = acc_lo.z;
    olo[(size_t)3 * HWL] = acc_lo.w;
    float* ohi = po + ((size_t)((b * LL + t_hi) * CC) + cg * 4) * HWL + pix;
    ohi[0]               = acc_hi.x;
    ohi[(size_t)1 * HWL] = acc_hi.y;
    ohi[(size_t)2 * HWL] = acc_hi.z;
    ohi[(size_t)3 * HWL] = acc_hi.w;
}

// Kernel 4: out += part, vectorized float4.
__global__ __launch_bounds__(256) void add_partial_kernel(
    const float* __restrict__ part, float* __restrict__ out) {
    int i = blockIdx.x * blockDim.x + threadIdx.x;
    if (i >= BB * LL * CC * HWL / 4) return;
    const float4* p4 = reinterpret_cast<const float4*>(part);
    float4* o4 = reinterpret_cast<float4*>(out);
    float4 a = o4[i], p = p4[i];
    a.x += p.x;
    a.y += p.y;
    a.z += p.z;
    a.w += p.w;
    o4[i] = a;
}

// Fallback (ws too small): fp32 scalar path on original layouts.
__global__ __launch_bounds__(256) void warp_pscan_fb(
    const float* __restrict__ cum, const float* __restrict__ images,
    float* __restrict__ out) {
    int idx = blockIdx.x * blockDim.x + threadIdx.x;
    if (idx >= BB * LL * HWL) return;
    int x  = idx & (WW - 1);
    int y  = (idx >> 6) & (HH - 1);
    int tl = (idx >> 12) & (LL - 1);
    int b  = idx >> 17;
    int t = (tl < 16) ? tl : (47 - tl);
    int pix = y * WW + x;
    float gx = -1.0f + (float)(2 * x + 1) * (1.0f / WW);
    float gy = -1.0f + (float)(2 * y + 1) * (1.0f / HH);
    const float* cumb = cum + (size_t)b * LL * 2 * HWL + pix;
    float ctx = cumb[(size_t)(2 * t) * HWL];
    float cty = cumb[(size_t)(2 * t + 1) * HWL];
    float acc[CC];
#pragma unroll
    for (int c = 0; c < CC; ++c) acc[c] = 0.0f;
    const float* imgb = images + (size_t)b * LL * CC * HWL;
    for (int k = 0; k <= t; ++k) {
        float dx = ctx - cumb[(size_t)(2 * k) * HWL];
        float dy = cty - cumb[(size_t)(2 * k + 1) * HWL];
        float g0 = gx + dx, g1 = gy + dy;
        float a = g0 + 1.0f, h = a * 0.5f;
        float rem = (h - floorf(h)) * 2.0f;
        float ix = fmaf(rem, 32.0f, -0.5f);
        float iy = fmaf(g1 + 1.0f, 32.0f, -0.5f);
        float x0f = floorf(ix), y0f = floorf(iy);
        float wx1 = ix - x0f, wy1 = iy - y0f;
        float wx0 = 1.0f - wx1, wy0 = 1.0f - wy1;
        int x0 = (int)x0f, y0 = (int)y0f;
        bool vx0 = x0 >= 0, vx1 = x0 < WW - 1;
        bool vy0 = (y0 >= 0) & (y0 < HH), vy1 = (y0 >= -1) & (y0 < HH - 1);
        int x0c = max(x0, 0), x1c = min(x0 + 1, WW - 1);
        int y0c = min(max(y0, 0), HH - 1), y1c = min(max(y0 + 1, 0), HH - 1);
        float w00 = (vx0 && vy0) ? wx0 * wy0 : 0.0f;
        float w10 = (vx1 && vy0) ? wx1 * wy0 : 0.0f;
        float w01 = (vx0 && vy1) ? wx0 * wy1 : 0.0f;
        float w11 = (vx1 && vy1) ? wx1 * wy1 : 0.0f;
        int o00 = y0c * WW + x0c, o10 = y0c * WW + x1c;
        int o01 = y1c * WW + x0c, o11 = y1c * WW + x1c;
        const float* ip = imgb + (size_t)k * CC * HWL;
#pragma unroll
        for (int c = 0; c < CC; ++c) {
            const float* ic = ip + (size_t)c * HWL;
            acc[c] += w00 * ic[o00] + w10 * ic[o10] + w01 * ic[o01] +
                      w11 * ic[o11];
        }
    }
    float* op = out + ((size_t)(b * LL + t) * CC) * HWL + pix;
#pragma unroll
    for (int c = 0; c < CC; ++c) op[(size_t)c * HWL] = acc[c];
}

extern "C" void kernel_launch(void* const* d_in, const int* in_sizes, int n_in,
                              void* d_out, int out_size, void* d_ws,
                              size_t ws_size, hipStream_t stream) {
    const float* flows  = (const float*)d_in[0];
    const float* images = (const float*)d_in[1];
    float* out = (float*)d_out;

    const size_t cum_bytes   = (size_t)BB * LL * 2 * HWL * sizeof(float);  // 2 MiB
    const size_t plane_bytes = (size_t)BB * LL * 2 * 4096 * 16;           // 8 MiB
    const size_t part_bytes  = (size_t)BB * LL * CC * HWL * sizeof(float); // 8 MiB
    float* cumB   = (float*)d_ws;
    float* planes = (float*)((char*)d_ws + cum_bytes);
    float* part   = (float*)((char*)d_ws + cum_bytes + plane_bytes);
    bool full = (ws_size >= cum_bytes + plane_bytes + part_bytes);

    int n1 = BB * 2 * HWL;
    cumsum_kernel<<<(n1 + 255) / 256, 256, 0, stream>>>(flows, cumB);

    if (full) {
        int n2 = BB * LL * HH * 32;
        repack_h2_kernel<<<(n2 + 255) / 256, 256, 0, stream>>>(images, planes);
        int n3 = 2 * 2 * BB * (LL / 2) * HWL;
        warp_pscan_v5<<<(n3 + 255) / 256, 256, 0, stream>>>(cumB, planes,
                                                            part, out);
        int n4 = BB * LL * CC * HWL / 4;
        add_partial_kernel<<<(n4 + 255) / 256, 256, 0, stream>>>(part, out);
    } else {
        int n3 = BB * LL * HWL;
        warp_pscan_fb<<<(n3 + 255) / 256, 256, 0, stream>>>(cumB, images, out);
    }
}